// Round 1
// baseline (1719.457 us; speedup 1.0000x reference)
//
#include <hip/hip_runtime.h>
#include <hip/hip_bf16.h>
#include <math.h>

#define FIN 35
#define FOUT 128
#define NGRAPHS 512

// ---------- helpers ----------
__device__ __forceinline__ unsigned int enc_f32(float f) {
    unsigned int u = __float_as_uint(f);
    return (u & 0x80000000u) ? ~u : (u | 0x80000000u);
}
__device__ __forceinline__ float dec_f32(unsigned int u) {
    unsigned int b = (u & 0x80000000u) ? (u ^ 0x80000000u) : ~u;
    return __uint_as_float(b);
}

// ---------- kernels ----------

// scatter-add x[src] into s[dst], one thread per (edge, feature).
// When do_cnt!=0 also count in-degree (f==0 lane).
__global__ void scatter_sum_kernel(const float* __restrict__ x,
                                   const int* __restrict__ src,
                                   const int* __restrict__ dst,
                                   float* __restrict__ s,
                                   int* __restrict__ cnt,
                                   int E, int do_cnt) {
    long long idx = (long long)blockIdx.x * blockDim.x + threadIdx.x;
    long long total = (long long)E * FIN;
    if (idx >= total) return;
    int e = (int)(idx / FIN);
    int f = (int)(idx - (long long)e * FIN);
    int sn = src[e];
    int dn = dst[e];
    atomicAdd(&s[(long long)dn * FIN + f], x[(long long)sn * FIN + f]);
    if (do_cnt && f == 0) atomicAdd(&cnt[dn], 1);
}

// h1 = relu( (s/cnt) @ Wl1 + bl1 + x @ Wr1 ), one thread per (node, out-feature)
__global__ void node_update1_kernel(const float* __restrict__ x,
                                    const float* __restrict__ s,
                                    const int* __restrict__ cnt,
                                    const float* __restrict__ Wl,
                                    const float* __restrict__ bl,
                                    const float* __restrict__ Wr,
                                    float* __restrict__ h,
                                    int N) {
    long long idx = (long long)blockIdx.x * blockDim.x + threadIdx.x;
    long long total = (long long)N * FIN;
    if (idx >= total) return;
    int n = (int)(idx / FIN);
    int j = (int)(idx - (long long)n * FIN);
    float inv = 1.0f / fmaxf((float)cnt[n], 1.0f);
    const float* srow = s + (long long)n * FIN;
    const float* xrow = x + (long long)n * FIN;
    float acc = bl[j];
    #pragma unroll
    for (int i = 0; i < FIN; ++i) {
        acc = fmaf(srow[i] * inv, Wl[i * FIN + j], acc);
        acc = fmaf(xrow[i],       Wr[i * FIN + j], acc);
    }
    h[(long long)n * FIN + j] = fmaxf(acc, 0.0f);
}

// h2 = (s/cnt) @ Wl2 + bl2 + h1 @ Wr2 ; then atomicMax into per-graph pool.
// one thread per (node, out-feature), FOUT=128
__global__ void node_update2_pool_kernel(const float* __restrict__ h1,
                                         const float* __restrict__ s,
                                         const int* __restrict__ cnt,
                                         const float* __restrict__ Wl,
                                         const float* __restrict__ bl,
                                         const float* __restrict__ Wr,
                                         const int* __restrict__ batch,
                                         unsigned int* __restrict__ genc,
                                         int N) {
    long long idx = (long long)blockIdx.x * blockDim.x + threadIdx.x;
    long long total = (long long)N * FOUT;
    if (idx >= total) return;
    int n = (int)(idx >> 7);
    int j = (int)(idx & 127);
    float inv = 1.0f / fmaxf((float)cnt[n], 1.0f);
    const float* srow = s  + (long long)n * FIN;
    const float* hrow = h1 + (long long)n * FIN;
    float acc = bl[j];
    #pragma unroll
    for (int i = 0; i < FIN; ++i) {
        acc = fmaf(srow[i] * inv, Wl[i * FOUT + j], acc);
        acc = fmaf(hrow[i],       Wr[i * FOUT + j], acc);
    }
    int b = batch[n];
    atomicMax(&genc[b * FOUT + j], enc_f32(acc));
}

// per-graph MLP head: relu(g@Wg1+bg1) -> relu(@Wg2+bg2) -> @Wo+bo
// one block (128 threads) per graph
__global__ void head_kernel(const unsigned int* __restrict__ genc,
                            const float* __restrict__ Wg1, const float* __restrict__ bg1,
                            const float* __restrict__ Wg2, const float* __restrict__ bg2,
                            const float* __restrict__ Wo,  const float* __restrict__ bo,
                            float* __restrict__ out) {
    __shared__ float a[FOUT];
    __shared__ float c[FOUT];
    __shared__ float red[2];
    int g = blockIdx.x;
    int j = threadIdx.x;

    a[j] = dec_f32(genc[g * FOUT + j]);
    __syncthreads();

    float acc = bg1[j];
    #pragma unroll 8
    for (int i = 0; i < FOUT; ++i) acc = fmaf(a[i], Wg1[i * FOUT + j], acc);
    c[j] = fmaxf(acc, 0.0f);
    __syncthreads();

    acc = bg2[j];
    #pragma unroll 8
    for (int i = 0; i < FOUT; ++i) acc = fmaf(c[i], Wg2[i * FOUT + j], acc);
    float t = fmaxf(acc, 0.0f) * Wo[j];

    // reduce t across 128 threads (2 waves of 64)
    #pragma unroll
    for (int off = 32; off > 0; off >>= 1) t += __shfl_down(t, off, 64);
    if ((threadIdx.x & 63) == 0) red[threadIdx.x >> 6] = t;
    __syncthreads();
    if (threadIdx.x == 0) out[g] = red[0] + red[1] + bo[0];
}

// ---------- launch ----------
extern "C" void kernel_launch(void* const* d_in, const int* in_sizes, int n_in,
                              void* d_out, int out_size, void* d_ws, size_t ws_size,
                              hipStream_t stream) {
    const float* x    = (const float*)d_in[0];
    const int*   ei   = (const int*)  d_in[1];
    const int*   batch= (const int*)  d_in[2];
    const float* Wl1  = (const float*)d_in[3];
    const float* bl1  = (const float*)d_in[4];
    const float* Wr1  = (const float*)d_in[5];
    const float* Wl2  = (const float*)d_in[6];
    const float* bl2  = (const float*)d_in[7];
    const float* Wr2  = (const float*)d_in[8];
    const float* Wg1  = (const float*)d_in[9];
    const float* bg1  = (const float*)d_in[10];
    const float* Wg2  = (const float*)d_in[11];
    const float* bg2  = (const float*)d_in[12];
    const float* Wo   = (const float*)d_in[13];
    const float* bo   = (const float*)d_in[14];
    float* out = (float*)d_out;

    const int N = in_sizes[0] / FIN;
    const int E = in_sizes[1] / 2;
    const int* src = ei;
    const int* dst = ei + E;

    // workspace layout
    char* ws = (char*)d_ws;
    size_t off = 0;
    int*          cnt  = (int*)(ws + off);          off += ((size_t)N * 4 + 255) & ~255ull;
    float*        s    = (float*)(ws + off);        off += ((size_t)N * FIN * 4 + 255) & ~255ull;
    float*        h1   = (float*)(ws + off);        off += ((size_t)N * FIN * 4 + 255) & ~255ull;
    unsigned int* genc = (unsigned int*)(ws + off); off += (size_t)NGRAPHS * FOUT * 4;
    (void)ws_size; (void)n_in; (void)out_size;

    const int BS = 256;
    long long scat_total = (long long)E * FIN;
    int scat_blocks = (int)((scat_total + BS - 1) / BS);
    long long nu1_total = (long long)N * FIN;
    int nu1_blocks = (int)((nu1_total + BS - 1) / BS);
    long long nu2_total = (long long)N * FOUT;
    int nu2_blocks = (int)((nu2_total + BS - 1) / BS);

    // ---- conv1 ----
    hipMemsetAsync(cnt, 0, (size_t)N * 4, stream);
    hipMemsetAsync(s,   0, (size_t)N * FIN * 4, stream);
    hipLaunchKernelGGL(scatter_sum_kernel, dim3(scat_blocks), dim3(BS), 0, stream,
                       x, src, dst, s, cnt, E, 1);
    hipLaunchKernelGGL(node_update1_kernel, dim3(nu1_blocks), dim3(BS), 0, stream,
                       x, s, cnt, Wl1, bl1, Wr1, h1, N);

    // ---- conv2 + pool ----
    hipMemsetAsync(s, 0, (size_t)N * FIN * 4, stream);
    hipMemsetAsync(genc, 0, (size_t)NGRAPHS * FOUT * 4, stream);
    hipLaunchKernelGGL(scatter_sum_kernel, dim3(scat_blocks), dim3(BS), 0, stream,
                       h1, src, dst, s, cnt, E, 0);
    hipLaunchKernelGGL(node_update2_pool_kernel, dim3(nu2_blocks), dim3(BS), 0, stream,
                       h1, s, cnt, Wl2, bl2, Wr2, batch, genc, N);

    // ---- head ----
    hipLaunchKernelGGL(head_kernel, dim3(NGRAPHS), dim3(FOUT), 0, stream,
                       genc, Wg1, bg1, Wg2, bg2, Wo, bo, out);
}

// Round 2
// 1165.790 us; speedup vs baseline: 1.4749x; 1.4749x over previous
//
#include <hip/hip_runtime.h>
#include <hip/hip_bf16.h>
#include <math.h>

#define FIN 35
#define FOUT 128
#define NGRAPHS 512

// ---------- helpers ----------
__device__ __forceinline__ unsigned int enc_f32(float f) {
    unsigned int u = __float_as_uint(f);
    return (u & 0x80000000u) ? ~u : (u | 0x80000000u);
}
__device__ __forceinline__ float dec_f32(unsigned int u) {
    unsigned int b = (u & 0x80000000u) ? (u ^ 0x80000000u) : ~u;
    return __uint_as_float(b);
}

// ---------- CSR build ----------

// degree count: one thread per edge
__global__ void deg_kernel(const int* __restrict__ dst, int* __restrict__ deg, int E) {
    int e = blockIdx.x * blockDim.x + threadIdx.x;
    if (e < E) atomicAdd(&deg[dst[e]], 1);
}

// per-256-chunk sums
__global__ void partial_reduce_kernel(const int* __restrict__ deg, int* __restrict__ partial, int N) {
    int i = blockIdx.x * 256 + threadIdx.x;
    int v = (i < N) ? deg[i] : 0;
    #pragma unroll
    for (int off = 32; off > 0; off >>= 1) v += __shfl_down(v, off, 64);
    __shared__ int w[4];
    if ((threadIdx.x & 63) == 0) w[threadIdx.x >> 6] = v;
    __syncthreads();
    if (threadIdx.x == 0) partial[blockIdx.x] = w[0] + w[1] + w[2] + w[3];
}

// exclusive scan of partials (single block, NB <= 1024)
__global__ void scan_partials_kernel(int* __restrict__ partial, int NB) {
    __shared__ int lds[1024];
    int t = threadIdx.x;
    int v = (t < NB) ? partial[t] : 0;
    lds[t] = v;
    __syncthreads();
    for (int off = 1; off < 1024; off <<= 1) {
        int tv = (t >= off) ? lds[t - off] : 0;
        __syncthreads();
        lds[t] += tv;
        __syncthreads();
    }
    if (t < NB) partial[t] = lds[t] - v;   // exclusive
}

// per-chunk scan + offset -> row_ptr (exclusive) and cursor copy
__global__ void scan_final_kernel(const int* __restrict__ deg, const int* __restrict__ partial,
                                  int* __restrict__ row_ptr, int* __restrict__ cursor, int N) {
    __shared__ int lds[256];
    int i = blockIdx.x * 256 + threadIdx.x;
    int v = (i < N) ? deg[i] : 0;
    lds[threadIdx.x] = v;
    __syncthreads();
    for (int off = 1; off < 256; off <<= 1) {
        int tv = (threadIdx.x >= off) ? lds[threadIdx.x - off] : 0;
        __syncthreads();
        lds[threadIdx.x] += tv;
        __syncthreads();
    }
    int excl = lds[threadIdx.x] - v + partial[blockIdx.x];
    if (i < N) {
        row_ptr[i] = excl;
        cursor[i] = excl;
        if (i == N - 1) row_ptr[N] = excl + v;
    }
}

// fill CSR adjacency (src ids grouped by dst)
__global__ void fill_kernel(const int* __restrict__ src, const int* __restrict__ dst,
                            int* __restrict__ cursor, int* __restrict__ esrc, int E) {
    int e = blockIdx.x * blockDim.x + threadIdx.x;
    if (e < E) {
        int d = dst[e];
        int p = atomicAdd(&cursor[d], 1);
        esrc[p] = src[e];
    }
}

// ---------- aggregation: s[n][f] = mean over CSR neighbors of x[src][f] ----------
__global__ void aggregate_kernel(const float* __restrict__ x,
                                 const int* __restrict__ row_ptr,
                                 const int* __restrict__ esrc,
                                 float* __restrict__ s, int N) {
    long long idx = (long long)blockIdx.x * blockDim.x + threadIdx.x;
    long long total = (long long)N * FIN;
    if (idx >= total) return;
    int n = (int)(idx / FIN);
    int f = (int)(idx - (long long)n * FIN);
    int b = row_ptr[n];
    int e = row_ptr[n + 1];
    float acc = 0.0f;
    for (int k = b; k < e; ++k) {
        acc += x[(long long)esrc[k] * FIN + f];
    }
    float inv = 1.0f / (float)max(e - b, 1);
    s[(long long)n * FIN + f] = acc * inv;
}

// ---------- node updates ----------

// h1 = relu( s @ Wl1 + bl1 + x @ Wr1 ), s already mean-aggregated
__global__ void node_update1_kernel(const float* __restrict__ x,
                                    const float* __restrict__ s,
                                    const float* __restrict__ Wl,
                                    const float* __restrict__ bl,
                                    const float* __restrict__ Wr,
                                    float* __restrict__ h,
                                    int N) {
    long long idx = (long long)blockIdx.x * blockDim.x + threadIdx.x;
    long long total = (long long)N * FIN;
    if (idx >= total) return;
    int n = (int)(idx / FIN);
    int j = (int)(idx - (long long)n * FIN);
    const float* srow = s + (long long)n * FIN;
    const float* xrow = x + (long long)n * FIN;
    float acc = bl[j];
    #pragma unroll
    for (int i = 0; i < FIN; ++i) {
        acc = fmaf(srow[i], Wl[i * FIN + j], acc);
        acc = fmaf(xrow[i], Wr[i * FIN + j], acc);
    }
    h[(long long)n * FIN + j] = fmaxf(acc, 0.0f);
}

// h2 = s @ Wl2 + bl2 + h1 @ Wr2 ; atomicMax into per-graph pool
__global__ void node_update2_pool_kernel(const float* __restrict__ h1,
                                         const float* __restrict__ s,
                                         const float* __restrict__ Wl,
                                         const float* __restrict__ bl,
                                         const float* __restrict__ Wr,
                                         const int* __restrict__ batch,
                                         unsigned int* __restrict__ genc,
                                         int N) {
    long long idx = (long long)blockIdx.x * blockDim.x + threadIdx.x;
    long long total = (long long)N * FOUT;
    if (idx >= total) return;
    int n = (int)(idx >> 7);
    int j = (int)(idx & 127);
    const float* srow = s  + (long long)n * FIN;
    const float* hrow = h1 + (long long)n * FIN;
    float acc = bl[j];
    #pragma unroll
    for (int i = 0; i < FIN; ++i) {
        acc = fmaf(srow[i], Wl[i * FOUT + j], acc);
        acc = fmaf(hrow[i], Wr[i * FOUT + j], acc);
    }
    int b = batch[n];
    atomicMax(&genc[b * FOUT + j], enc_f32(acc));
}

// ---------- head: one block (128 threads) per graph ----------
__global__ void head_kernel(const unsigned int* __restrict__ genc,
                            const float* __restrict__ Wg1, const float* __restrict__ bg1,
                            const float* __restrict__ Wg2, const float* __restrict__ bg2,
                            const float* __restrict__ Wo,  const float* __restrict__ bo,
                            float* __restrict__ out) {
    __shared__ float a[FOUT];
    __shared__ float c[FOUT];
    __shared__ float red[2];
    int g = blockIdx.x;
    int j = threadIdx.x;

    a[j] = dec_f32(genc[g * FOUT + j]);
    __syncthreads();

    float acc = bg1[j];
    #pragma unroll 8
    for (int i = 0; i < FOUT; ++i) acc = fmaf(a[i], Wg1[i * FOUT + j], acc);
    c[j] = fmaxf(acc, 0.0f);
    __syncthreads();

    acc = bg2[j];
    #pragma unroll 8
    for (int i = 0; i < FOUT; ++i) acc = fmaf(c[i], Wg2[i * FOUT + j], acc);
    float t = fmaxf(acc, 0.0f) * Wo[j];

    #pragma unroll
    for (int off = 32; off > 0; off >>= 1) t += __shfl_down(t, off, 64);
    if ((threadIdx.x & 63) == 0) red[threadIdx.x >> 6] = t;
    __syncthreads();
    if (threadIdx.x == 0) out[g] = red[0] + red[1] + bo[0];
}

// ---------- launch ----------
extern "C" void kernel_launch(void* const* d_in, const int* in_sizes, int n_in,
                              void* d_out, int out_size, void* d_ws, size_t ws_size,
                              hipStream_t stream) {
    const float* x    = (const float*)d_in[0];
    const int*   ei   = (const int*)  d_in[1];
    const int*   batch= (const int*)  d_in[2];
    const float* Wl1  = (const float*)d_in[3];
    const float* bl1  = (const float*)d_in[4];
    const float* Wr1  = (const float*)d_in[5];
    const float* Wl2  = (const float*)d_in[6];
    const float* bl2  = (const float*)d_in[7];
    const float* Wr2  = (const float*)d_in[8];
    const float* Wg1  = (const float*)d_in[9];
    const float* bg1  = (const float*)d_in[10];
    const float* Wg2  = (const float*)d_in[11];
    const float* bg2  = (const float*)d_in[12];
    const float* Wo   = (const float*)d_in[13];
    const float* bo   = (const float*)d_in[14];
    float* out = (float*)d_out;

    const int N = in_sizes[0] / FIN;
    const int E = in_sizes[1] / 2;
    const int* src = ei;
    const int* dst = ei + E;
    const int NB = (N + 255) / 256;   // 391 for N=100000 (must be <=1024)

    // workspace layout
    char* ws = (char*)d_ws;
    size_t off = 0;
    auto alloc = [&](size_t bytes) { char* p = ws + off; off += (bytes + 255) & ~255ull; return p; };
    int*          deg     = (int*)alloc((size_t)N * 4);
    int*          row_ptr = (int*)alloc((size_t)(N + 1) * 4);
    int*          cursor  = (int*)alloc((size_t)N * 4);
    int*          partial = (int*)alloc(1024 * 4);
    int*          esrc    = (int*)alloc((size_t)E * 4);
    float*        s       = (float*)alloc((size_t)N * FIN * 4);
    float*        h1      = (float*)alloc((size_t)N * FIN * 4);
    unsigned int* genc    = (unsigned int*)alloc((size_t)NGRAPHS * FOUT * 4);
    (void)ws_size; (void)n_in; (void)out_size;

    const int BS = 256;
    int eb = (E + BS - 1) / BS;
    long long aggt = (long long)N * FIN;
    int aggb = (int)((aggt + BS - 1) / BS);
    long long nu2t = (long long)N * FOUT;
    int nu2b = (int)((nu2t + BS - 1) / BS);

    // ---- CSR build (once, reused by both conv layers) ----
    hipMemsetAsync(deg, 0, (size_t)N * 4, stream);
    hipLaunchKernelGGL(deg_kernel, dim3(eb), dim3(BS), 0, stream, dst, deg, E);
    hipLaunchKernelGGL(partial_reduce_kernel, dim3(NB), dim3(BS), 0, stream, deg, partial, N);
    hipLaunchKernelGGL(scan_partials_kernel, dim3(1), dim3(1024), 0, stream, partial, NB);
    hipLaunchKernelGGL(scan_final_kernel, dim3(NB), dim3(BS), 0, stream, deg, partial, row_ptr, cursor, N);
    hipLaunchKernelGGL(fill_kernel, dim3(eb), dim3(BS), 0, stream, src, dst, cursor, esrc, E);

    // ---- conv1 ----
    hipLaunchKernelGGL(aggregate_kernel, dim3(aggb), dim3(BS), 0, stream, x, row_ptr, esrc, s, N);
    hipLaunchKernelGGL(node_update1_kernel, dim3(aggb), dim3(BS), 0, stream, x, s, Wl1, bl1, Wr1, h1, N);

    // ---- conv2 + pool ----
    hipLaunchKernelGGL(aggregate_kernel, dim3(aggb), dim3(BS), 0, stream, h1, row_ptr, esrc, s, N);
    hipMemsetAsync(genc, 0, (size_t)NGRAPHS * FOUT * 4, stream);
    hipLaunchKernelGGL(node_update2_pool_kernel, dim3(nu2b), dim3(BS), 0, stream,
                       h1, s, Wl2, bl2, Wr2, batch, genc, N);

    // ---- head ----
    hipLaunchKernelGGL(head_kernel, dim3(NGRAPHS), dim3(FOUT), 0, stream,
                       genc, Wg1, bg1, Wg2, bg2, Wo, bo, out);
}

// Round 3
// 891.157 us; speedup vs baseline: 1.9295x; 1.3082x over previous
//
#include <hip/hip_runtime.h>
#include <hip/hip_bf16.h>
#include <math.h>

#define FIN 35
#define FOUT 128
#define NGRAPHS 512
#define EPT 8     // edges per thread in deg/fill
#define STRIP 16  // nodes per block in nu2

// ---------- helpers ----------
__device__ __forceinline__ unsigned int enc_f32(float f) {
    unsigned int u = __float_as_uint(f);
    return (u & 0x80000000u) ? ~u : (u | 0x80000000u);
}
__device__ __forceinline__ float dec_f32(unsigned int u) {
    unsigned int b = (u & 0x80000000u) ? (u ^ 0x80000000u) : ~u;
    return __uint_as_float(b);
}

// ---------- CSR build ----------

// degree count: EPT edges per thread, coalesced per u-iteration, 8 independent atomics in flight
__global__ void deg_kernel(const int* __restrict__ dst, int* __restrict__ deg, int E) {
    int tid = blockIdx.x * blockDim.x + threadIdx.x;
    int stride = gridDim.x * blockDim.x;
    #pragma unroll
    for (int u = 0; u < EPT; ++u) {
        int e = tid + u * stride;
        if (e < E) atomicAdd(&deg[dst[e]], 1);
    }
}

// per-256-chunk sums
__global__ void partial_reduce_kernel(const int* __restrict__ deg, int* __restrict__ partial, int N) {
    int i = blockIdx.x * 256 + threadIdx.x;
    int v = (i < N) ? deg[i] : 0;
    #pragma unroll
    for (int off = 32; off > 0; off >>= 1) v += __shfl_down(v, off, 64);
    __shared__ int w[4];
    if ((threadIdx.x & 63) == 0) w[threadIdx.x >> 6] = v;
    __syncthreads();
    if (threadIdx.x == 0) partial[blockIdx.x] = w[0] + w[1] + w[2] + w[3];
}

// exclusive scan of partials (single block, NB <= 1024)
__global__ void scan_partials_kernel(int* __restrict__ partial, int NB) {
    __shared__ int lds[1024];
    int t = threadIdx.x;
    int v = (t < NB) ? partial[t] : 0;
    lds[t] = v;
    __syncthreads();
    for (int off = 1; off < 1024; off <<= 1) {
        int tv = (t >= off) ? lds[t - off] : 0;
        __syncthreads();
        lds[t] += tv;
        __syncthreads();
    }
    if (t < NB) partial[t] = lds[t] - v;   // exclusive
}

// per-chunk scan + offset -> row_ptr (exclusive) and cursor copy
__global__ void scan_final_kernel(const int* __restrict__ deg, const int* __restrict__ partial,
                                  int* __restrict__ row_ptr, int* __restrict__ cursor, int N) {
    __shared__ int lds[256];
    int i = blockIdx.x * 256 + threadIdx.x;
    int v = (i < N) ? deg[i] : 0;
    lds[threadIdx.x] = v;
    __syncthreads();
    for (int off = 1; off < 256; off <<= 1) {
        int tv = (threadIdx.x >= off) ? lds[threadIdx.x - off] : 0;
        __syncthreads();
        lds[threadIdx.x] += tv;
        __syncthreads();
    }
    int excl = lds[threadIdx.x] - v + partial[blockIdx.x];
    if (i < N) {
        row_ptr[i] = excl;
        cursor[i] = excl;
        if (i == N - 1) row_ptr[N] = excl + v;
    }
}

// fill CSR adjacency: EPT edges per thread, 8 independent atomic+store chains in flight
__global__ void fill_kernel(const int* __restrict__ src, const int* __restrict__ dst,
                            int* __restrict__ cursor, int* __restrict__ esrc, int E) {
    int tid = blockIdx.x * blockDim.x + threadIdx.x;
    int stride = gridDim.x * blockDim.x;
    #pragma unroll
    for (int u = 0; u < EPT; ++u) {
        int e = tid + u * stride;
        if (e < E) {
            int d = dst[e];
            int p = atomicAdd(&cursor[d], 1);
            esrc[p] = src[e];
        }
    }
}

// ---------- aggregation: s[n][f] = mean over CSR neighbors of x[src][f] ----------
__global__ void aggregate_kernel(const float* __restrict__ x,
                                 const int* __restrict__ row_ptr,
                                 const int* __restrict__ esrc,
                                 float* __restrict__ s, int N) {
    long long idx = (long long)blockIdx.x * blockDim.x + threadIdx.x;
    long long total = (long long)N * FIN;
    if (idx >= total) return;
    int n = (int)(idx / FIN);
    int f = (int)(idx - (long long)n * FIN);
    int b = row_ptr[n];
    int e = row_ptr[n + 1];
    float a0 = 0.0f, a1 = 0.0f, a2 = 0.0f, a3 = 0.0f;
    int k = b;
    for (; k + 4 <= e; k += 4) {
        int s0 = esrc[k], s1 = esrc[k + 1], s2 = esrc[k + 2], s3 = esrc[k + 3];
        a0 += x[(long long)s0 * FIN + f];
        a1 += x[(long long)s1 * FIN + f];
        a2 += x[(long long)s2 * FIN + f];
        a3 += x[(long long)s3 * FIN + f];
    }
    for (; k < e; ++k) a0 += x[(long long)esrc[k] * FIN + f];
    float acc = (a0 + a1) + (a2 + a3);
    float inv = 1.0f / (float)max(e - b, 1);
    s[(long long)n * FIN + f] = acc * inv;
}

// ---------- node updates ----------

// h1 = relu( s @ Wl1 + bl1 + x @ Wr1 )
__global__ void node_update1_kernel(const float* __restrict__ x,
                                    const float* __restrict__ s,
                                    const float* __restrict__ Wl,
                                    const float* __restrict__ bl,
                                    const float* __restrict__ Wr,
                                    float* __restrict__ h,
                                    int N) {
    long long idx = (long long)blockIdx.x * blockDim.x + threadIdx.x;
    long long total = (long long)N * FIN;
    if (idx >= total) return;
    int n = (int)(idx / FIN);
    int j = (int)(idx - (long long)n * FIN);
    const float* srow = s + (long long)n * FIN;
    const float* xrow = x + (long long)n * FIN;
    float acc = bl[j];
    #pragma unroll
    for (int i = 0; i < FIN; ++i) {
        acc = fmaf(srow[i], Wl[i * FIN + j], acc);
        acc = fmaf(xrow[i], Wr[i * FIN + j], acc);
    }
    h[(long long)n * FIN + j] = fmaxf(acc, 0.0f);
}

// h2 = s @ Wl2 + bl2 + h1 @ Wr2 ; pooled max per graph with segment-batched atomics.
// One block (128 j-threads) per strip of 16 consecutive nodes; batch is sorted,
// so a running max is flushed only on graph change -> ~16x fewer atomics.
__global__ __launch_bounds__(128) void node_update2_pool_kernel(
        const float* __restrict__ h1,
        const float* __restrict__ s,
        const float* __restrict__ Wl,
        const float* __restrict__ bl,
        const float* __restrict__ Wr,
        const int* __restrict__ batch,
        unsigned int* __restrict__ genc,
        int N) {
    __shared__ float s_sh[STRIP * FIN];
    __shared__ float h_sh[STRIP * FIN];
    __shared__ int b_sh[STRIP];
    int node0 = blockIdx.x * STRIP;
    if (node0 >= N) return;
    int nn_count = min(STRIP, N - node0);
    int tot = nn_count * FIN;
    for (int t = threadIdx.x; t < tot; t += 128) {
        s_sh[t] = s[(long long)node0 * FIN + t];
        h_sh[t] = h1[(long long)node0 * FIN + t];
    }
    if (threadIdx.x < nn_count) b_sh[threadIdx.x] = batch[node0 + threadIdx.x];
    __syncthreads();

    int j = threadIdx.x;
    float wl[FIN], wr[FIN];
    #pragma unroll
    for (int i = 0; i < FIN; ++i) {
        wl[i] = Wl[i * FOUT + j];
        wr[i] = Wr[i * FOUT + j];
    }
    float blj = bl[j];

    int curg = b_sh[0];
    float m = -INFINITY;
    for (int nn = 0; nn < nn_count; ++nn) {
        float acc = blj;
        #pragma unroll
        for (int i = 0; i < FIN; ++i) {
            acc = fmaf(s_sh[nn * FIN + i], wl[i], acc);
            acc = fmaf(h_sh[nn * FIN + i], wr[i], acc);
        }
        int g = b_sh[nn];   // wave-uniform
        if (g != curg) {
            atomicMax(&genc[curg * FOUT + j], enc_f32(m));
            curg = g;
            m = acc;
        } else {
            m = fmaxf(m, acc);
        }
    }
    atomicMax(&genc[curg * FOUT + j], enc_f32(m));
}

// ---------- head: one block (128 threads) per graph ----------
__global__ void head_kernel(const unsigned int* __restrict__ genc,
                            const float* __restrict__ Wg1, const float* __restrict__ bg1,
                            const float* __restrict__ Wg2, const float* __restrict__ bg2,
                            const float* __restrict__ Wo,  const float* __restrict__ bo,
                            float* __restrict__ out) {
    __shared__ float a[FOUT];
    __shared__ float c[FOUT];
    __shared__ float red[2];
    int g = blockIdx.x;
    int j = threadIdx.x;

    a[j] = dec_f32(genc[g * FOUT + j]);
    __syncthreads();

    float acc = bg1[j];
    #pragma unroll 8
    for (int i = 0; i < FOUT; ++i) acc = fmaf(a[i], Wg1[i * FOUT + j], acc);
    c[j] = fmaxf(acc, 0.0f);
    __syncthreads();

    acc = bg2[j];
    #pragma unroll 8
    for (int i = 0; i < FOUT; ++i) acc = fmaf(c[i], Wg2[i * FOUT + j], acc);
    float t = fmaxf(acc, 0.0f) * Wo[j];

    #pragma unroll
    for (int off = 32; off > 0; off >>= 1) t += __shfl_down(t, off, 64);
    if ((threadIdx.x & 63) == 0) red[threadIdx.x >> 6] = t;
    __syncthreads();
    if (threadIdx.x == 0) out[g] = red[0] + red[1] + bo[0];
}

// ---------- launch ----------
extern "C" void kernel_launch(void* const* d_in, const int* in_sizes, int n_in,
                              void* d_out, int out_size, void* d_ws, size_t ws_size,
                              hipStream_t stream) {
    const float* x    = (const float*)d_in[0];
    const int*   ei   = (const int*)  d_in[1];
    const int*   batch= (const int*)  d_in[2];
    const float* Wl1  = (const float*)d_in[3];
    const float* bl1  = (const float*)d_in[4];
    const float* Wr1  = (const float*)d_in[5];
    const float* Wl2  = (const float*)d_in[6];
    const float* bl2  = (const float*)d_in[7];
    const float* Wr2  = (const float*)d_in[8];
    const float* Wg1  = (const float*)d_in[9];
    const float* bg1  = (const float*)d_in[10];
    const float* Wg2  = (const float*)d_in[11];
    const float* bg2  = (const float*)d_in[12];
    const float* Wo   = (const float*)d_in[13];
    const float* bo   = (const float*)d_in[14];
    float* out = (float*)d_out;

    const int N = in_sizes[0] / FIN;
    const int E = in_sizes[1] / 2;
    const int* src = ei;
    const int* dst = ei + E;
    const int NB = (N + 255) / 256;   // 391 for N=100000 (must be <=1024)

    // workspace layout
    char* ws = (char*)d_ws;
    size_t off = 0;
    auto alloc = [&](size_t bytes) { char* p = ws + off; off += (bytes + 255) & ~255ull; return p; };
    int*          deg     = (int*)alloc((size_t)N * 4);
    int*          row_ptr = (int*)alloc((size_t)(N + 1) * 4);
    int*          cursor  = (int*)alloc((size_t)N * 4);
    int*          partial = (int*)alloc(1024 * 4);
    int*          esrc    = (int*)alloc((size_t)E * 4);
    float*        s       = (float*)alloc((size_t)N * FIN * 4);
    float*        h1      = (float*)alloc((size_t)N * FIN * 4);
    unsigned int* genc    = (unsigned int*)alloc((size_t)NGRAPHS * FOUT * 4);
    (void)ws_size; (void)n_in; (void)out_size;

    const int BS = 256;
    int eb  = (E + BS * EPT - 1) / (BS * EPT);   // deg/fill grids (EPT edges/thread)
    long long aggt = (long long)N * FIN;
    int aggb = (int)((aggt + BS - 1) / BS);
    int nu2b = (N + STRIP - 1) / STRIP;

    // ---- CSR build (once, reused by both conv layers) ----
    hipMemsetAsync(deg, 0, (size_t)N * 4, stream);
    hipLaunchKernelGGL(deg_kernel, dim3(eb), dim3(BS), 0, stream, dst, deg, E);
    hipLaunchKernelGGL(partial_reduce_kernel, dim3(NB), dim3(BS), 0, stream, deg, partial, N);
    hipLaunchKernelGGL(scan_partials_kernel, dim3(1), dim3(1024), 0, stream, partial, NB);
    hipLaunchKernelGGL(scan_final_kernel, dim3(NB), dim3(BS), 0, stream, deg, partial, row_ptr, cursor, N);
    hipLaunchKernelGGL(fill_kernel, dim3(eb), dim3(BS), 0, stream, src, dst, cursor, esrc, E);

    // ---- conv1 ----
    hipLaunchKernelGGL(aggregate_kernel, dim3(aggb), dim3(BS), 0, stream, x, row_ptr, esrc, s, N);
    hipLaunchKernelGGL(node_update1_kernel, dim3(aggb), dim3(BS), 0, stream, x, s, Wl1, bl1, Wr1, h1, N);

    // ---- conv2 + pool ----
    hipLaunchKernelGGL(aggregate_kernel, dim3(aggb), dim3(BS), 0, stream, h1, row_ptr, esrc, s, N);
    hipMemsetAsync(genc, 0, (size_t)NGRAPHS * FOUT * 4, stream);
    hipLaunchKernelGGL(node_update2_pool_kernel, dim3(nu2b), dim3(128), 0, stream,
                       h1, s, Wl2, bl2, Wr2, batch, genc, N);

    // ---- head ----
    hipLaunchKernelGGL(head_kernel, dim3(NGRAPHS), dim3(FOUT), 0, stream,
                       genc, Wg1, bg1, Wg2, bg2, Wo, bo, out);
}

// Round 4
// 646.557 us; speedup vs baseline: 2.6594x; 1.3783x over previous
//
#include <hip/hip_runtime.h>
#include <hip/hip_bf16.h>
#include <math.h>

#define FIN 35
#define FOUT 128
#define NGRAPHS 512
#define STRIP 16  // nodes per block in nu2

// ---------- helpers ----------
__device__ __forceinline__ unsigned int enc_f32(float f) {
    unsigned int u = __float_as_uint(f);
    return (u & 0x80000000u) ? ~u : (u | 0x80000000u);
}
__device__ __forceinline__ float dec_f32(unsigned int u) {
    unsigned int b = (u & 0x80000000u) ? (u ^ 0x80000000u) : ~u;
    return __uint_as_float(b);
}

// ---------- CSR build ----------

// degree + per-edge rank capture in one pass: the atomic's return value IS the rank.
__global__ void deg_rank_kernel(const int* __restrict__ dst, int* __restrict__ deg,
                                int* __restrict__ erank, int E) {
    int e = blockIdx.x * blockDim.x + threadIdx.x;
    if (e < E) erank[e] = atomicAdd(&deg[dst[e]], 1);   // erank store is coalesced
}

// per-256-chunk sums
__global__ void partial_reduce_kernel(const int* __restrict__ deg, int* __restrict__ partial, int N) {
    int i = blockIdx.x * 256 + threadIdx.x;
    int v = (i < N) ? deg[i] : 0;
    #pragma unroll
    for (int off = 32; off > 0; off >>= 1) v += __shfl_down(v, off, 64);
    __shared__ int w[4];
    if ((threadIdx.x & 63) == 0) w[threadIdx.x >> 6] = v;
    __syncthreads();
    if (threadIdx.x == 0) partial[blockIdx.x] = w[0] + w[1] + w[2] + w[3];
}

// exclusive scan of partials (single block, NB <= 1024)
__global__ void scan_partials_kernel(int* __restrict__ partial, int NB) {
    __shared__ int lds[1024];
    int t = threadIdx.x;
    int v = (t < NB) ? partial[t] : 0;
    lds[t] = v;
    __syncthreads();
    for (int off = 1; off < 1024; off <<= 1) {
        int tv = (t >= off) ? lds[t - off] : 0;
        __syncthreads();
        lds[t] += tv;
        __syncthreads();
    }
    if (t < NB) partial[t] = lds[t] - v;   // exclusive
}

// per-chunk scan + offset -> row_ptr (exclusive)
__global__ void scan_final_kernel(const int* __restrict__ deg, const int* __restrict__ partial,
                                  int* __restrict__ row_ptr, int N) {
    __shared__ int lds[256];
    int i = blockIdx.x * 256 + threadIdx.x;
    int v = (i < N) ? deg[i] : 0;
    lds[threadIdx.x] = v;
    __syncthreads();
    for (int off = 1; off < 256; off <<= 1) {
        int tv = (threadIdx.x >= off) ? lds[threadIdx.x - off] : 0;
        __syncthreads();
        lds[threadIdx.x] += tv;
        __syncthreads();
    }
    int excl = lds[threadIdx.x] - v + partial[blockIdx.x];
    if (i < N) {
        row_ptr[i] = excl;
        if (i == N - 1) row_ptr[N] = excl + v;
    }
}

// fill CSR adjacency with precomputed ranks: no atomic, fire-and-forget scattered store.
__global__ void fill_kernel(const int* __restrict__ src, const int* __restrict__ dst,
                            const int* __restrict__ row_ptr, const int* __restrict__ erank,
                            int* __restrict__ esrc, int E) {
    int e = blockIdx.x * blockDim.x + threadIdx.x;
    if (e < E) {
        esrc[row_ptr[dst[e]] + erank[e]] = src[e];
    }
}

// ---------- aggregation: s[n][f] = mean over CSR neighbors of x[src][f] ----------
__global__ void aggregate_kernel(const float* __restrict__ x,
                                 const int* __restrict__ row_ptr,
                                 const int* __restrict__ esrc,
                                 float* __restrict__ s, int N) {
    long long idx = (long long)blockIdx.x * blockDim.x + threadIdx.x;
    long long total = (long long)N * FIN;
    if (idx >= total) return;
    int n = (int)(idx / FIN);
    int f = (int)(idx - (long long)n * FIN);
    int b = row_ptr[n];
    int e = row_ptr[n + 1];
    float a0 = 0.0f, a1 = 0.0f, a2 = 0.0f, a3 = 0.0f;
    int k = b;
    for (; k + 4 <= e; k += 4) {
        int s0 = esrc[k], s1 = esrc[k + 1], s2 = esrc[k + 2], s3 = esrc[k + 3];
        a0 += x[(long long)s0 * FIN + f];
        a1 += x[(long long)s1 * FIN + f];
        a2 += x[(long long)s2 * FIN + f];
        a3 += x[(long long)s3 * FIN + f];
    }
    for (; k < e; ++k) a0 += x[(long long)esrc[k] * FIN + f];
    float acc = (a0 + a1) + (a2 + a3);
    float inv = 1.0f / (float)max(e - b, 1);
    s[(long long)n * FIN + f] = acc * inv;
}

// ---------- node updates ----------

// h1 = relu( s @ Wl1 + bl1 + x @ Wr1 )
__global__ void node_update1_kernel(const float* __restrict__ x,
                                    const float* __restrict__ s,
                                    const float* __restrict__ Wl,
                                    const float* __restrict__ bl,
                                    const float* __restrict__ Wr,
                                    float* __restrict__ h,
                                    int N) {
    long long idx = (long long)blockIdx.x * blockDim.x + threadIdx.x;
    long long total = (long long)N * FIN;
    if (idx >= total) return;
    int n = (int)(idx / FIN);
    int j = (int)(idx - (long long)n * FIN);
    const float* srow = s + (long long)n * FIN;
    const float* xrow = x + (long long)n * FIN;
    float acc = bl[j];
    #pragma unroll
    for (int i = 0; i < FIN; ++i) {
        acc = fmaf(srow[i], Wl[i * FIN + j], acc);
        acc = fmaf(xrow[i], Wr[i * FIN + j], acc);
    }
    h[(long long)n * FIN + j] = fmaxf(acc, 0.0f);
}

// h2 = s @ Wl2 + bl2 + h1 @ Wr2 ; pooled max per graph, segment-batched atomics.
__global__ __launch_bounds__(128) void node_update2_pool_kernel(
        const float* __restrict__ h1,
        const float* __restrict__ s,
        const float* __restrict__ Wl,
        const float* __restrict__ bl,
        const float* __restrict__ Wr,
        const int* __restrict__ batch,
        unsigned int* __restrict__ genc,
        int N) {
    __shared__ float s_sh[STRIP * FIN];
    __shared__ float h_sh[STRIP * FIN];
    __shared__ int b_sh[STRIP];
    int node0 = blockIdx.x * STRIP;
    if (node0 >= N) return;
    int nn_count = min(STRIP, N - node0);
    int tot = nn_count * FIN;
    for (int t = threadIdx.x; t < tot; t += 128) {
        s_sh[t] = s[(long long)node0 * FIN + t];
        h_sh[t] = h1[(long long)node0 * FIN + t];
    }
    if (threadIdx.x < nn_count) b_sh[threadIdx.x] = batch[node0 + threadIdx.x];
    __syncthreads();

    int j = threadIdx.x;
    float wl[FIN], wr[FIN];
    #pragma unroll
    for (int i = 0; i < FIN; ++i) {
        wl[i] = Wl[i * FOUT + j];
        wr[i] = Wr[i * FOUT + j];
    }
    float blj = bl[j];

    int curg = b_sh[0];
    float m = -INFINITY;
    for (int nn = 0; nn < nn_count; ++nn) {
        float acc = blj;
        #pragma unroll
        for (int i = 0; i < FIN; ++i) {
            acc = fmaf(s_sh[nn * FIN + i], wl[i], acc);
            acc = fmaf(h_sh[nn * FIN + i], wr[i], acc);
        }
        int g = b_sh[nn];   // wave-uniform
        if (g != curg) {
            atomicMax(&genc[curg * FOUT + j], enc_f32(m));
            curg = g;
            m = acc;
        } else {
            m = fmaxf(m, acc);
        }
    }
    atomicMax(&genc[curg * FOUT + j], enc_f32(m));
}

// ---------- head: one block (128 threads) per graph ----------
__global__ void head_kernel(const unsigned int* __restrict__ genc,
                            const float* __restrict__ Wg1, const float* __restrict__ bg1,
                            const float* __restrict__ Wg2, const float* __restrict__ bg2,
                            const float* __restrict__ Wo,  const float* __restrict__ bo,
                            float* __restrict__ out) {
    __shared__ float a[FOUT];
    __shared__ float c[FOUT];
    __shared__ float red[2];
    int g = blockIdx.x;
    int j = threadIdx.x;

    a[j] = dec_f32(genc[g * FOUT + j]);
    __syncthreads();

    float acc = bg1[j];
    #pragma unroll 8
    for (int i = 0; i < FOUT; ++i) acc = fmaf(a[i], Wg1[i * FOUT + j], acc);
    c[j] = fmaxf(acc, 0.0f);
    __syncthreads();

    acc = bg2[j];
    #pragma unroll 8
    for (int i = 0; i < FOUT; ++i) acc = fmaf(c[i], Wg2[i * FOUT + j], acc);
    float t = fmaxf(acc, 0.0f) * Wo[j];

    #pragma unroll
    for (int off = 32; off > 0; off >>= 1) t += __shfl_down(t, off, 64);
    if ((threadIdx.x & 63) == 0) red[threadIdx.x >> 6] = t;
    __syncthreads();
    if (threadIdx.x == 0) out[g] = red[0] + red[1] + bo[0];
}

// ---------- launch ----------
extern "C" void kernel_launch(void* const* d_in, const int* in_sizes, int n_in,
                              void* d_out, int out_size, void* d_ws, size_t ws_size,
                              hipStream_t stream) {
    const float* x    = (const float*)d_in[0];
    const int*   ei   = (const int*)  d_in[1];
    const int*   batch= (const int*)  d_in[2];
    const float* Wl1  = (const float*)d_in[3];
    const float* bl1  = (const float*)d_in[4];
    const float* Wr1  = (const float*)d_in[5];
    const float* Wl2  = (const float*)d_in[6];
    const float* bl2  = (const float*)d_in[7];
    const float* Wr2  = (const float*)d_in[8];
    const float* Wg1  = (const float*)d_in[9];
    const float* bg1  = (const float*)d_in[10];
    const float* Wg2  = (const float*)d_in[11];
    const float* bg2  = (const float*)d_in[12];
    const float* Wo   = (const float*)d_in[13];
    const float* bo   = (const float*)d_in[14];
    float* out = (float*)d_out;

    const int N = in_sizes[0] / FIN;
    const int E = in_sizes[1] / 2;
    const int* src = ei;
    const int* dst = ei + E;
    const int NB = (N + 255) / 256;   // 391 for N=100000 (must be <=1024)

    // workspace layout
    char* ws = (char*)d_ws;
    size_t off = 0;
    auto alloc = [&](size_t bytes) { char* p = ws + off; off += (bytes + 255) & ~255ull; return p; };
    int*          deg     = (int*)alloc((size_t)N * 4);
    int*          row_ptr = (int*)alloc((size_t)(N + 1) * 4);
    int*          partial = (int*)alloc(1024 * 4);
    int*          erank   = (int*)alloc((size_t)E * 4);
    int*          esrc    = (int*)alloc((size_t)E * 4);
    float*        s       = (float*)alloc((size_t)N * FIN * 4);
    float*        h1      = (float*)alloc((size_t)N * FIN * 4);
    unsigned int* genc    = (unsigned int*)alloc((size_t)NGRAPHS * FOUT * 4);
    (void)ws_size; (void)n_in; (void)out_size;

    const int BS = 256;
    int eb = (E + BS - 1) / BS;                 // 1 edge/thread
    long long aggt = (long long)N * FIN;
    int aggb = (int)((aggt + BS - 1) / BS);
    int nu2b = (N + STRIP - 1) / STRIP;

    // ---- CSR build (once, reused by both conv layers) ----
    hipMemsetAsync(deg, 0, (size_t)N * 4, stream);
    hipLaunchKernelGGL(deg_rank_kernel, dim3(eb), dim3(BS), 0, stream, dst, deg, erank, E);
    hipLaunchKernelGGL(partial_reduce_kernel, dim3(NB), dim3(BS), 0, stream, deg, partial, N);
    hipLaunchKernelGGL(scan_partials_kernel, dim3(1), dim3(1024), 0, stream, partial, NB);
    hipLaunchKernelGGL(scan_final_kernel, dim3(NB), dim3(BS), 0, stream, deg, partial, row_ptr, N);
    hipLaunchKernelGGL(fill_kernel, dim3(eb), dim3(BS), 0, stream, src, dst, row_ptr, erank, esrc, E);

    // ---- conv1 ----
    hipLaunchKernelGGL(aggregate_kernel, dim3(aggb), dim3(BS), 0, stream, x, row_ptr, esrc, s, N);
    hipLaunchKernelGGL(node_update1_kernel, dim3(aggb), dim3(BS), 0, stream, x, s, Wl1, bl1, Wr1, h1, N);

    // ---- conv2 + pool ----
    hipLaunchKernelGGL(aggregate_kernel, dim3(aggb), dim3(BS), 0, stream, h1, row_ptr, esrc, s, N);
    hipMemsetAsync(genc, 0, (size_t)NGRAPHS * FOUT * 4, stream);
    hipLaunchKernelGGL(node_update2_pool_kernel, dim3(nu2b), dim3(128), 0, stream,
                       h1, s, Wl2, bl2, Wr2, batch, genc, N);

    // ---- head ----
    hipLaunchKernelGGL(head_kernel, dim3(NGRAPHS), dim3(FOUT), 0, stream,
                       genc, Wg1, bg1, Wg2, bg2, Wo, bo, out);
}

// Round 5
// 542.677 us; speedup vs baseline: 3.1685x; 1.1914x over previous
//
#include <hip/hip_runtime.h>
#include <hip/hip_bf16.h>
#include <math.h>

#define FIN 35
#define FOUT 128
#define NGRAPHS 512
#define STRIP 16        // nodes per block in nu2
#define CHUNK 8192      // edges per block in hist1/scatter1
#define MAXBUCK 512     // >= ceil(N/256)

// ---------- helpers ----------
__device__ __forceinline__ unsigned int enc_f32(float f) {
    unsigned int u = __float_as_uint(f);
    return (u & 0x80000000u) ? ~u : (u | 0x80000000u);
}
__device__ __forceinline__ float dec_f32(unsigned int u) {
    unsigned int b = (u & 0x80000000u) ? (u ^ 0x80000000u) : ~u;
    return __uint_as_float(b);
}

// ---------- CSR build via two-level LDS radix partition (no global atomics) ----------

// Level-1 histogram: per-chunk LDS histogram over buckets (bucket = dst>>8).
__global__ __launch_bounds__(256) void hist1_kernel(const int* __restrict__ dst,
                                                    int* __restrict__ counts,
                                                    int E, int nblk1, int nbuck) {
    __shared__ int h[MAXBUCK];
    for (int t = threadIdx.x; t < nbuck; t += 256) h[t] = 0;
    __syncthreads();
    int base = blockIdx.x * CHUNK;
    int end = min(base + CHUNK, E);
    for (int e = base + threadIdx.x; e < end; e += 256)
        atomicAdd(&h[dst[e] >> 8], 1);
    __syncthreads();
    for (int t = threadIdx.x; t < nbuck; t += 256)
        counts[t * nblk1 + blockIdx.x] = h[t];
}

// generic scan helpers (SC elements, SC <= 256*1024)
__global__ void partial_reduce_kernel(const int* __restrict__ v_in, int* __restrict__ partial, int SC) {
    int i = blockIdx.x * 256 + threadIdx.x;
    int v = (i < SC) ? v_in[i] : 0;
    #pragma unroll
    for (int off = 32; off > 0; off >>= 1) v += __shfl_down(v, off, 64);
    __shared__ int w[4];
    if ((threadIdx.x & 63) == 0) w[threadIdx.x >> 6] = v;
    __syncthreads();
    if (threadIdx.x == 0) partial[blockIdx.x] = w[0] + w[1] + w[2] + w[3];
}

__global__ void scan_partials_kernel(int* __restrict__ partial, int NB) {
    __shared__ int lds[1024];
    int t = threadIdx.x;
    int v = (t < NB) ? partial[t] : 0;
    lds[t] = v;
    __syncthreads();
    for (int off = 1; off < 1024; off <<= 1) {
        int tv = (t >= off) ? lds[t - off] : 0;
        __syncthreads();
        lds[t] += tv;
        __syncthreads();
    }
    if (t < NB) partial[t] = lds[t] - v;   // exclusive
}

__global__ void scan_final_kernel(const int* __restrict__ v_in, const int* __restrict__ partial,
                                  int* __restrict__ outx, int SC) {
    __shared__ int lds[256];
    int i = blockIdx.x * 256 + threadIdx.x;
    int v = (i < SC) ? v_in[i] : 0;
    lds[threadIdx.x] = v;
    __syncthreads();
    for (int off = 1; off < 256; off <<= 1) {
        int tv = (threadIdx.x >= off) ? lds[threadIdx.x - off] : 0;
        __syncthreads();
        lds[threadIdx.x] += tv;
        __syncthreads();
    }
    int excl = lds[threadIdx.x] - v + partial[blockIdx.x];
    if (i < SC) {
        outx[i] = excl;
        if (i == SC - 1) outx[SC] = excl + v;
    }
}

// Level-1 scatter: pack (src<<8)|dst_local into bucket-partitioned ebuf via LDS cursors.
__global__ __launch_bounds__(256) void scatter1_kernel(const int* __restrict__ src,
                                                       const int* __restrict__ dst,
                                                       const int* __restrict__ offs,
                                                       int* __restrict__ ebuf,
                                                       int E, int nblk1, int nbuck) {
    __shared__ int cur[MAXBUCK];
    for (int t = threadIdx.x; t < nbuck; t += 256) cur[t] = offs[t * nblk1 + blockIdx.x];
    __syncthreads();
    int base = blockIdx.x * CHUNK;
    int end = min(base + CHUNK, E);
    for (int e = base + threadIdx.x; e < end; e += 256) {
        int d = dst[e];
        int p = atomicAdd(&cur[d >> 8], 1);
        ebuf[p] = (src[e] << 8) | (d & 255);
    }
}

// Level-2: one block per bucket (256 node ids). LDS hist + scan -> row_ptr, LDS-cursor scatter -> esrc.
__global__ __launch_bounds__(256) void csr2_kernel(const int* __restrict__ ebuf,
                                                   const int* __restrict__ offs,
                                                   int* __restrict__ row_ptr,
                                                   int* __restrict__ esrc,
                                                   int E, int nblk1, int nbuck, int N) {
    __shared__ int h[256];
    __shared__ int scn[256];
    int b = blockIdx.x;
    int t = threadIdx.x;
    int bstart = offs[b * nblk1];
    int bend = (b + 1 < nbuck) ? offs[(b + 1) * nblk1] : E;

    h[t] = 0;
    __syncthreads();
    for (int k = bstart + t; k < bend; k += 256)
        atomicAdd(&h[ebuf[k] & 255], 1);
    __syncthreads();

    int v = h[t];
    scn[t] = v;
    __syncthreads();
    for (int off = 1; off < 256; off <<= 1) {
        int tv = (t >= off) ? scn[t - off] : 0;
        __syncthreads();
        scn[t] += tv;
        __syncthreads();
    }
    int excl = scn[t] - v;
    int node = (b << 8) + t;
    if (node < N) row_ptr[node] = bstart + excl;
    if (b == 0 && t == 0) row_ptr[N] = E;

    // reuse h as write cursor
    __syncthreads();
    h[t] = bstart + excl;
    __syncthreads();
    for (int k = bstart + t; k < bend; k += 256) {
        int e = ebuf[k];
        int p = atomicAdd(&h[e & 255], 1);
        esrc[p] = e >> 8;
    }
}

// ---------- aggregation: s[n][f] = mean over CSR neighbors of x[src][f] ----------
__global__ void aggregate_kernel(const float* __restrict__ x,
                                 const int* __restrict__ row_ptr,
                                 const int* __restrict__ esrc,
                                 float* __restrict__ s, int N) {
    long long idx = (long long)blockIdx.x * blockDim.x + threadIdx.x;
    long long total = (long long)N * FIN;
    if (idx >= total) return;
    int n = (int)(idx / FIN);
    int f = (int)(idx - (long long)n * FIN);
    int b = row_ptr[n];
    int e = row_ptr[n + 1];
    float a0 = 0.0f, a1 = 0.0f, a2 = 0.0f, a3 = 0.0f;
    int k = b;
    for (; k + 4 <= e; k += 4) {
        int s0 = esrc[k], s1 = esrc[k + 1], s2 = esrc[k + 2], s3 = esrc[k + 3];
        a0 += x[(long long)s0 * FIN + f];
        a1 += x[(long long)s1 * FIN + f];
        a2 += x[(long long)s2 * FIN + f];
        a3 += x[(long long)s3 * FIN + f];
    }
    for (; k < e; ++k) a0 += x[(long long)esrc[k] * FIN + f];
    float acc = (a0 + a1) + (a2 + a3);
    float inv = 1.0f / (float)max(e - b, 1);
    s[(long long)n * FIN + f] = acc * inv;
}

// ---------- node updates ----------

__global__ void node_update1_kernel(const float* __restrict__ x,
                                    const float* __restrict__ s,
                                    const float* __restrict__ Wl,
                                    const float* __restrict__ bl,
                                    const float* __restrict__ Wr,
                                    float* __restrict__ h,
                                    int N) {
    long long idx = (long long)blockIdx.x * blockDim.x + threadIdx.x;
    long long total = (long long)N * FIN;
    if (idx >= total) return;
    int n = (int)(idx / FIN);
    int j = (int)(idx - (long long)n * FIN);
    const float* srow = s + (long long)n * FIN;
    const float* xrow = x + (long long)n * FIN;
    float acc = bl[j];
    #pragma unroll
    for (int i = 0; i < FIN; ++i) {
        acc = fmaf(srow[i], Wl[i * FIN + j], acc);
        acc = fmaf(xrow[i], Wr[i * FIN + j], acc);
    }
    h[(long long)n * FIN + j] = fmaxf(acc, 0.0f);
}

// h2 = s @ Wl2 + bl2 + h1 @ Wr2 ; pooled max per graph, segment-batched atomics.
__global__ __launch_bounds__(128) void node_update2_pool_kernel(
        const float* __restrict__ h1,
        const float* __restrict__ s,
        const float* __restrict__ Wl,
        const float* __restrict__ bl,
        const float* __restrict__ Wr,
        const int* __restrict__ batch,
        unsigned int* __restrict__ genc,
        int N) {
    __shared__ float s_sh[STRIP * FIN];
    __shared__ float h_sh[STRIP * FIN];
    __shared__ int b_sh[STRIP];
    int node0 = blockIdx.x * STRIP;
    if (node0 >= N) return;
    int nn_count = min(STRIP, N - node0);
    int tot = nn_count * FIN;
    for (int t = threadIdx.x; t < tot; t += 128) {
        s_sh[t] = s[(long long)node0 * FIN + t];
        h_sh[t] = h1[(long long)node0 * FIN + t];
    }
    if (threadIdx.x < nn_count) b_sh[threadIdx.x] = batch[node0 + threadIdx.x];
    __syncthreads();

    int j = threadIdx.x;
    float wl[FIN], wr[FIN];
    #pragma unroll
    for (int i = 0; i < FIN; ++i) {
        wl[i] = Wl[i * FOUT + j];
        wr[i] = Wr[i * FOUT + j];
    }
    float blj = bl[j];

    int curg = b_sh[0];
    float m = -INFINITY;
    for (int nn = 0; nn < nn_count; ++nn) {
        float acc = blj;
        #pragma unroll
        for (int i = 0; i < FIN; ++i) {
            acc = fmaf(s_sh[nn * FIN + i], wl[i], acc);
            acc = fmaf(h_sh[nn * FIN + i], wr[i], acc);
        }
        int g = b_sh[nn];   // wave-uniform
        if (g != curg) {
            atomicMax(&genc[curg * FOUT + j], enc_f32(m));
            curg = g;
            m = acc;
        } else {
            m = fmaxf(m, acc);
        }
    }
    atomicMax(&genc[curg * FOUT + j], enc_f32(m));
}

// ---------- head: one block (128 threads) per graph ----------
__global__ void head_kernel(const unsigned int* __restrict__ genc,
                            const float* __restrict__ Wg1, const float* __restrict__ bg1,
                            const float* __restrict__ Wg2, const float* __restrict__ bg2,
                            const float* __restrict__ Wo,  const float* __restrict__ bo,
                            float* __restrict__ out) {
    __shared__ float a[FOUT];
    __shared__ float c[FOUT];
    __shared__ float red[2];
    int g = blockIdx.x;
    int j = threadIdx.x;

    a[j] = dec_f32(genc[g * FOUT + j]);
    __syncthreads();

    float acc = bg1[j];
    #pragma unroll 8
    for (int i = 0; i < FOUT; ++i) acc = fmaf(a[i], Wg1[i * FOUT + j], acc);
    c[j] = fmaxf(acc, 0.0f);
    __syncthreads();

    acc = bg2[j];
    #pragma unroll 8
    for (int i = 0; i < FOUT; ++i) acc = fmaf(c[i], Wg2[i * FOUT + j], acc);
    float t = fmaxf(acc, 0.0f) * Wo[j];

    #pragma unroll
    for (int off = 32; off > 0; off >>= 1) t += __shfl_down(t, off, 64);
    if ((threadIdx.x & 63) == 0) red[threadIdx.x >> 6] = t;
    __syncthreads();
    if (threadIdx.x == 0) out[g] = red[0] + red[1] + bo[0];
}

// ---------- launch ----------
extern "C" void kernel_launch(void* const* d_in, const int* in_sizes, int n_in,
                              void* d_out, int out_size, void* d_ws, size_t ws_size,
                              hipStream_t stream) {
    const float* x    = (const float*)d_in[0];
    const int*   ei   = (const int*)  d_in[1];
    const int*   batch= (const int*)  d_in[2];
    const float* Wl1  = (const float*)d_in[3];
    const float* bl1  = (const float*)d_in[4];
    const float* Wr1  = (const float*)d_in[5];
    const float* Wl2  = (const float*)d_in[6];
    const float* bl2  = (const float*)d_in[7];
    const float* Wr2  = (const float*)d_in[8];
    const float* Wg1  = (const float*)d_in[9];
    const float* bg1  = (const float*)d_in[10];
    const float* Wg2  = (const float*)d_in[11];
    const float* bg2  = (const float*)d_in[12];
    const float* Wo   = (const float*)d_in[13];
    const float* bo   = (const float*)d_in[14];
    float* out = (float*)d_out;

    const int N = in_sizes[0] / FIN;
    const int E = in_sizes[1] / 2;
    const int* src = ei;
    const int* dst = ei + E;

    const int nblk1 = (E + CHUNK - 1) / CHUNK;          // 391
    const int nbuck = (N + 255) >> 8;                   // 391 (<= MAXBUCK)
    const int SC = nbuck * nblk1;                       // 152881
    const int NB2 = (SC + 255) / 256;                   // 598 (<= 1024)

    // workspace layout
    char* ws = (char*)d_ws;
    size_t off = 0;
    auto alloc = [&](size_t bytes) { char* p = ws + off; off += (bytes + 255) & ~255ull; return p; };
    int*          counts  = (int*)alloc((size_t)SC * 4);
    int*          offs    = (int*)alloc((size_t)(SC + 1) * 4);
    int*          partial = (int*)alloc(1024 * 4);
    int*          row_ptr = (int*)alloc((size_t)(N + 1) * 4);
    int*          ebuf    = (int*)alloc((size_t)E * 4);
    int*          esrc    = (int*)alloc((size_t)E * 4);
    float*        s       = (float*)alloc((size_t)N * FIN * 4);
    float*        h1      = (float*)alloc((size_t)N * FIN * 4);
    unsigned int* genc    = (unsigned int*)alloc((size_t)NGRAPHS * FOUT * 4);
    (void)ws_size; (void)n_in; (void)out_size;

    const int BS = 256;
    long long aggt = (long long)N * FIN;
    int aggb = (int)((aggt + BS - 1) / BS);
    int nu2b = (N + STRIP - 1) / STRIP;

    // ---- CSR build (LDS radix, no global atomics; reused by both conv layers) ----
    hipLaunchKernelGGL(hist1_kernel, dim3(nblk1), dim3(BS), 0, stream, dst, counts, E, nblk1, nbuck);
    hipLaunchKernelGGL(partial_reduce_kernel, dim3(NB2), dim3(BS), 0, stream, counts, partial, SC);
    hipLaunchKernelGGL(scan_partials_kernel, dim3(1), dim3(1024), 0, stream, partial, NB2);
    hipLaunchKernelGGL(scan_final_kernel, dim3(NB2), dim3(BS), 0, stream, counts, partial, offs, SC);
    hipLaunchKernelGGL(scatter1_kernel, dim3(nblk1), dim3(BS), 0, stream, src, dst, offs, ebuf, E, nblk1, nbuck);
    hipLaunchKernelGGL(csr2_kernel, dim3(nbuck), dim3(BS), 0, stream, ebuf, offs, row_ptr, esrc, E, nblk1, nbuck, N);

    // ---- conv1 ----
    hipLaunchKernelGGL(aggregate_kernel, dim3(aggb), dim3(BS), 0, stream, x, row_ptr, esrc, s, N);
    hipLaunchKernelGGL(node_update1_kernel, dim3(aggb), dim3(BS), 0, stream, x, s, Wl1, bl1, Wr1, h1, N);

    // ---- conv2 + pool ----
    hipLaunchKernelGGL(aggregate_kernel, dim3(aggb), dim3(BS), 0, stream, h1, row_ptr, esrc, s, N);
    hipMemsetAsync(genc, 0, (size_t)NGRAPHS * FOUT * 4, stream);
    hipLaunchKernelGGL(node_update2_pool_kernel, dim3(nu2b), dim3(128), 0, stream,
                       h1, s, Wl2, bl2, Wr2, batch, genc, N);

    // ---- head ----
    hipLaunchKernelGGL(head_kernel, dim3(NGRAPHS), dim3(FOUT), 0, stream,
                       genc, Wg1, bg1, Wg2, bg2, Wo, bo, out);
}